// Round 1
// baseline (736.549 us; speedup 1.0000x reference)
//
#include <hip/hip_runtime.h>

#define EPSV 0.001f
#define NCTX 16
#define DIM  64

// ws layout (floats)
#define WS_S1    0      // 16*64
#define WS_S2    1024   // 16*64
#define WS_CNT   2048   // 16
#define WS_SCALE 2112   // 16*64 (16B-aligned: 2112*4 = 8448 bytes)
#define WS_SHIFT 3136   // 16*64

// ---------------- Pass 1: per-context cnt / sum / sumsq ----------------
// One wave per row; lane = dim. LDS fp32 atomics per row, global atomics
// once per block.
__global__ __launch_bounds__(256) void stats_kernel(
    const float* __restrict__ samples,
    const int* __restrict__ contexts,
    float* __restrict__ ws, int N) {
  __shared__ float s1[NCTX * DIM];
  __shared__ float s2[NCTX * DIM];
  __shared__ float cnt[NCTX];

  int tid = threadIdx.x;
  for (int i = tid; i < NCTX * DIM; i += blockDim.x) { s1[i] = 0.f; s2[i] = 0.f; }
  if (tid < NCTX) cnt[tid] = 0.f;
  __syncthreads();

  int lane = tid & 63;
  int wv   = tid >> 6;
  int wpb  = blockDim.x >> 6;
  int gw   = blockIdx.x * wpb + wv;      // global wave id
  int nw   = gridDim.x * wpb;            // total waves

  #pragma unroll 4
  for (int row = gw; row < N; row += nw) {
    int   c = contexts[row];
    float v = samples[row * DIM + lane];
    atomicAdd(&s1[c * DIM + lane], v);
    atomicAdd(&s2[c * DIM + lane], v * v);
    if (lane == 0) atomicAdd(&cnt[c], 1.0f);
  }
  __syncthreads();

  for (int i = tid; i < NCTX * DIM; i += blockDim.x) {
    atomicAdd(&ws[WS_S1 + i], s1[i]);
    atomicAdd(&ws[WS_S2 + i], s2[i]);
  }
  if (tid < NCTX) atomicAdd(&ws[WS_CNT + tid], cnt[tid]);
}

// ---------------- Pass 2: finalize scale/shift (16x64) ----------------
__global__ __launch_bounds__(1024) void finalize_kernel(
    const float* __restrict__ gamma,
    const float* __restrict__ beta,
    const float* __restrict__ priors,
    float* __restrict__ ws) {
  int i = threadIdx.x;        // 0..1023 = c*64 + d
  int c = i >> 6;
  float cntv  = ws[WS_CNT + c];
  float safe  = fmaxf(cntv, 1.0f);
  float mean  = ws[WS_S1 + i] / safe;
  float var   = ws[WS_S2 + i] / safe - mean * mean;
  float istd  = rsqrtf(var + EPSV);
  float ps    = rsqrtf(priors[c]);
  float g     = gamma[i];
  float scale = g * istd * ps;
  float shift = (beta[i] - g * mean * istd) * ps;
  if (!(cntv > 0.f)) { scale = 1.f; shift = 0.f; }  // where(cnt>0, y, x)
  ws[WS_SCALE + i] = scale;
  ws[WS_SHIFT + i] = shift;
}

// ---------------- Pass 3: y = x * scale[c] + shift[c] ----------------
// float4 per thread; scale/shift staged in LDS as float4.
__global__ __launch_bounds__(256) void norm_kernel(
    const float4* __restrict__ samples4,
    const int* __restrict__ contexts,
    const float* __restrict__ ws,
    float4* __restrict__ out4, int n4) {
  __shared__ float4 sc[NCTX * DIM / 4];
  __shared__ float4 sh[NCTX * DIM / 4];
  const float4* wsc = (const float4*)(ws + WS_SCALE);
  const float4* wsh = (const float4*)(ws + WS_SHIFT);
  for (int i = threadIdx.x; i < NCTX * DIM / 4; i += blockDim.x) {
    sc[i] = wsc[i];
    sh[i] = wsh[i];
  }
  __syncthreads();

  int stride = gridDim.x * blockDim.x;
  for (int i = blockIdx.x * blockDim.x + threadIdx.x; i < n4; i += stride) {
    int row = i >> 4;          // 16 float4 per row (D=64)
    int d4  = i & 15;
    int c   = contexts[row];
    float4 v = samples4[i];
    float4 a = sc[c * 16 + d4];
    float4 b = sh[c * 16 + d4];
    float4 r;
    r.x = fmaf(v.x, a.x, b.x);
    r.y = fmaf(v.y, a.y, b.y);
    r.z = fmaf(v.z, a.z, b.z);
    r.w = fmaf(v.w, a.w, b.w);
    out4[i] = r;
  }
}

extern "C" void kernel_launch(void* const* d_in, const int* in_sizes, int n_in,
                              void* d_out, int out_size, void* d_ws, size_t ws_size,
                              hipStream_t stream) {
  const float* samples  = (const float*)d_in[0];
  const int*   contexts = (const int*)d_in[1];
  const float* gamma    = (const float*)d_in[2];
  const float* beta     = (const float*)d_in[3];
  const float* priors   = (const float*)d_in[4];
  float* out = (float*)d_out;
  float* ws  = (float*)d_ws;

  int N = in_sizes[1];  // contexts has N elements

  // Zero the stats region every call (harness doesn't re-poison between
  // timed replays; we own ws initialization). Graph-capture safe.
  hipMemsetAsync(ws, 0, WS_SCALE * sizeof(float), stream);

  stats_kernel<<<2048, 256, 0, stream>>>(samples, contexts, ws, N);
  finalize_kernel<<<1, 1024, 0, stream>>>(gamma, beta, priors, ws);

  int n4 = N * (DIM / 4);
  norm_kernel<<<4096, 256, 0, stream>>>((const float4*)samples, contexts, ws,
                                        (float4*)out, n4);
}

// Round 2
// 358.758 us; speedup vs baseline: 2.0531x; 2.0531x over previous
//
#include <hip/hip_runtime.h>

#define EPSV 0.001f
#define NCTX 16
#define DIM  64

// ws layout (floats):
//   [0, 1024)     scale (16 ctx x 64 dim)
//   [1024, 2048)  shift
//   [2048, 2048 + nb*2064)  per-block partials: s1[1024], s2[1024], cnt[16]
#define WS_SCALE 0
#define WS_SHIFT 1024
#define WS_PART  2048
#define PART_STRIDE 2064

// ---------------- Pass 1: per-block partial stats, no atomics ----------------
// One wave per row-stream; lane = dim. Context is wave-uniform per row, so a
// 16-way uniform switch accumulates into constant-indexed register arrays.
__global__ __launch_bounds__(256) void stats_kernel(
    const float* __restrict__ samples,
    const int* __restrict__ contexts,
    float* __restrict__ part, int N) {
  int tid  = threadIdx.x;
  int lane = tid & 63;
  int wv   = tid >> 6;
  int gw   = blockIdx.x * 4 + wv;
  int nw   = gridDim.x * 4;

  float s1a[NCTX], s2a[NCTX], cna[NCTX];
#pragma unroll
  for (int k = 0; k < NCTX; ++k) { s1a[k] = 0.f; s2a[k] = 0.f; cna[k] = 0.f; }

  // software-pipelined grid-stride loop (1-deep prefetch)
  int row = gw;
  float v = 0.f; int c = -1;
  if (row < N) { v = samples[(size_t)row * DIM + lane]; c = contexts[row]; }
  while (row < N) {
    int nrow = row + nw;
    float vn = 0.f; int cn = -1;
    if (nrow < N) { vn = samples[(size_t)nrow * DIM + lane]; cn = contexts[nrow]; }
#define CASE_K(k) case k: s1a[k] += v; s2a[k] += v * v; cna[k] += 1.f; break;
    switch (c) {
      CASE_K(0)  CASE_K(1)  CASE_K(2)  CASE_K(3)
      CASE_K(4)  CASE_K(5)  CASE_K(6)  CASE_K(7)
      CASE_K(8)  CASE_K(9)  CASE_K(10) CASE_K(11)
      CASE_K(12) CASE_K(13) CASE_K(14) CASE_K(15)
      default: break;
    }
#undef CASE_K
    v = vn; c = cn; row = nrow;
  }

  // block-level reduce across the 4 waves (non-atomic), write partials
  __shared__ float red[4][NCTX * DIM];
  float* pb = part + (size_t)blockIdx.x * PART_STRIDE;

#pragma unroll
  for (int k = 0; k < NCTX; ++k) red[wv][k * DIM + lane] = s1a[k];
  __syncthreads();
  for (int i = tid; i < NCTX * DIM; i += 256)
    pb[i] = red[0][i] + red[1][i] + red[2][i] + red[3][i];
  __syncthreads();

#pragma unroll
  for (int k = 0; k < NCTX; ++k) red[wv][k * DIM + lane] = s2a[k];
  __syncthreads();
  for (int i = tid; i < NCTX * DIM; i += 256)
    pb[1024 + i] = red[0][i] + red[1][i] + red[2][i] + red[3][i];
  __syncthreads();

  if (lane == 0) {
#pragma unroll
    for (int k = 0; k < NCTX; ++k) red[wv][k] = cna[k];
  }
  __syncthreads();
  if (tid < NCTX)
    pb[2048 + tid] = red[0][tid] + red[1][tid] + red[2][tid] + red[3][tid];
}

// ---------------- Pass 2: reduce partials + finalize scale/shift ----------------
// One block per context; coalesced 256B reads per wave per partial block.
__global__ __launch_bounds__(256) void reduce_finalize_kernel(
    const float* __restrict__ part,
    const float* __restrict__ gamma,
    const float* __restrict__ beta,
    const float* __restrict__ priors,
    float* __restrict__ ws, int nb) {
  int c   = blockIdx.x;
  int tid = threadIdx.x;
  int d   = tid & 63;
  int g   = tid >> 6;

  float a1 = 0.f, a2 = 0.f, ac = 0.f;
  for (int b = g; b < nb; b += 4) {
    const float* p = part + (size_t)b * PART_STRIDE;
    a1 += p[c * DIM + d];
    a2 += p[1024 + c * DIM + d];
    if (d == 0) ac += p[2048 + c];
  }

  __shared__ float r1[4][DIM], r2[4][DIM], rc[4];
  r1[g][d] = a1;
  r2[g][d] = a2;
  if (d == 0) rc[g] = ac;
  __syncthreads();

  if (tid < DIM) {
    float s1  = r1[0][tid] + r1[1][tid] + r1[2][tid] + r1[3][tid];
    float s2  = r2[0][tid] + r2[1][tid] + r2[2][tid] + r2[3][tid];
    float cnt = rc[0] + rc[1] + rc[2] + rc[3];
    float safe = fmaxf(cnt, 1.f);
    float mean = s1 / safe;
    float var  = s2 / safe - mean * mean;
    float istd = rsqrtf(var + EPSV);
    float ps   = rsqrtf(priors[c]);
    float gm   = gamma[c * DIM + tid];
    float scale = gm * istd * ps;
    float shift = (beta[c * DIM + tid] - gm * mean * istd) * ps;
    if (!(cnt > 0.f)) { scale = 1.f; shift = 0.f; }  // where(cnt>0, y, x)
    ws[WS_SCALE + c * DIM + tid] = scale;
    ws[WS_SHIFT + c * DIM + tid] = shift;
  }
}

// ---------------- Pass 3: y = x * scale[c] + shift[c] ----------------
__global__ __launch_bounds__(256) void norm_kernel(
    const float4* __restrict__ samples4,
    const int* __restrict__ contexts,
    const float* __restrict__ ws,
    float4* __restrict__ out4, int n4) {
  __shared__ float4 sc[NCTX * DIM / 4];
  __shared__ float4 sh[NCTX * DIM / 4];
  const float4* wsc = (const float4*)(ws + WS_SCALE);
  const float4* wsh = (const float4*)(ws + WS_SHIFT);
  for (int i = threadIdx.x; i < NCTX * DIM / 4; i += blockDim.x) {
    sc[i] = wsc[i];
    sh[i] = wsh[i];
  }
  __syncthreads();

  int stride = gridDim.x * blockDim.x;
  for (int i = blockIdx.x * blockDim.x + threadIdx.x; i < n4; i += stride) {
    int row = i >> 4;          // 16 float4 per row (D=64)
    int d4  = i & 15;
    int c   = contexts[row];
    float4 v = samples4[i];
    float4 a = sc[c * 16 + d4];
    float4 b = sh[c * 16 + d4];
    float4 r;
    r.x = fmaf(v.x, a.x, b.x);
    r.y = fmaf(v.y, a.y, b.y);
    r.z = fmaf(v.z, a.z, b.z);
    r.w = fmaf(v.w, a.w, b.w);
    out4[i] = r;
  }
}

extern "C" void kernel_launch(void* const* d_in, const int* in_sizes, int n_in,
                              void* d_out, int out_size, void* d_ws, size_t ws_size,
                              hipStream_t stream) {
  const float* samples  = (const float*)d_in[0];
  const int*   contexts = (const int*)d_in[1];
  const float* gamma    = (const float*)d_in[2];
  const float* beta     = (const float*)d_in[3];
  const float* priors   = (const float*)d_in[4];
  float* out = (float*)d_out;
  float* ws  = (float*)d_ws;

  int N = in_sizes[1];  // contexts has N elements

  // pick partial-block count that fits ws (16.9 MB at nb=2048)
  size_t availf = ws_size / sizeof(float);
  int nb = 2048;
  while (nb > 16 && (size_t)WS_PART + (size_t)nb * PART_STRIDE > availf) nb >>= 1;

  stats_kernel<<<nb, 256, 0, stream>>>(samples, contexts, ws + WS_PART, N);
  reduce_finalize_kernel<<<16, 256, 0, stream>>>(ws + WS_PART, gamma, beta,
                                                 priors, ws, nb);

  int n4 = N * (DIM / 4);
  norm_kernel<<<4096, 256, 0, stream>>>((const float4*)samples, contexts, ws,
                                        (float4*)out, n4);
}

// Round 3
// 211.744 us; speedup vs baseline: 3.4785x; 1.6943x over previous
//
#include <hip/hip_runtime.h>

#define EPSV 0.001f
#define NCTX 16
#define DIM  64
#define NSLICE 16
#define PART_STRIDE 2080   // floats per partial block: s1[1024] s2[1024] cnt[16] pad
#define P2_STRIDE   132    // per (ctx,slice): s1[64] s2[64] cnt[1] pad

// ws layout (floats): [0,1024) scale; [1024,2048) shift;
// [2048, 2048+nb*PART_STRIDE) stage-1 partials; then 16*16*P2_STRIDE stage-2.
#define WS_SCALE 0
#define WS_SHIFT 1024
#define WS_PART  2048

// ---------------- Pass 1: per-block partial stats, no atomics ----------------
// One wave per row-stream; lane = dim; context is wave-uniform per row ->
// scalarized 16-way switch into constant-indexed register accumulators.
// Unroll x4 for memory-level parallelism.
__global__ __launch_bounds__(256) void stats_kernel(
    const float* __restrict__ samples,
    const int* __restrict__ contexts,
    float* __restrict__ part, int N) {
  int tid  = threadIdx.x;
  int lane = tid & 63;
  int wv   = tid >> 6;
  int gw   = blockIdx.x * 4 + wv;
  int nw   = gridDim.x * 4;

  float s1a[NCTX], s2a[NCTX], cna[NCTX];
#pragma unroll
  for (int k = 0; k < NCTX; ++k) { s1a[k] = 0.f; s2a[k] = 0.f; cna[k] = 0.f; }

#define ACCUM(c, v)                                                        \
  switch (c) {                                                             \
    case 0:  s1a[0]  += v; s2a[0]  += v * v; cna[0]  += 1.f; break;        \
    case 1:  s1a[1]  += v; s2a[1]  += v * v; cna[1]  += 1.f; break;        \
    case 2:  s1a[2]  += v; s2a[2]  += v * v; cna[2]  += 1.f; break;        \
    case 3:  s1a[3]  += v; s2a[3]  += v * v; cna[3]  += 1.f; break;        \
    case 4:  s1a[4]  += v; s2a[4]  += v * v; cna[4]  += 1.f; break;        \
    case 5:  s1a[5]  += v; s2a[5]  += v * v; cna[5]  += 1.f; break;        \
    case 6:  s1a[6]  += v; s2a[6]  += v * v; cna[6]  += 1.f; break;        \
    case 7:  s1a[7]  += v; s2a[7]  += v * v; cna[7]  += 1.f; break;        \
    case 8:  s1a[8]  += v; s2a[8]  += v * v; cna[8]  += 1.f; break;        \
    case 9:  s1a[9]  += v; s2a[9]  += v * v; cna[9]  += 1.f; break;        \
    case 10: s1a[10] += v; s2a[10] += v * v; cna[10] += 1.f; break;        \
    case 11: s1a[11] += v; s2a[11] += v * v; cna[11] += 1.f; break;        \
    case 12: s1a[12] += v; s2a[12] += v * v; cna[12] += 1.f; break;        \
    case 13: s1a[13] += v; s2a[13] += v * v; cna[13] += 1.f; break;        \
    case 14: s1a[14] += v; s2a[14] += v * v; cna[14] += 1.f; break;        \
    case 15: s1a[15] += v; s2a[15] += v * v; cna[15] += 1.f; break;        \
    default: break;                                                        \
  }

  int step = nw * 4;
  for (int row = gw; row < N; row += step) {
    int r1 = row + nw, r2 = row + 2 * nw, r3 = row + 3 * nw;
    float v0, v1 = 0.f, v2 = 0.f, v3 = 0.f;
    int   c0, c1 = -1, c2 = -1, c3 = -1;
    v0 = samples[(size_t)row * DIM + lane]; c0 = contexts[row];
    if (r1 < N) { v1 = samples[(size_t)r1 * DIM + lane]; c1 = contexts[r1]; }
    if (r2 < N) { v2 = samples[(size_t)r2 * DIM + lane]; c2 = contexts[r2]; }
    if (r3 < N) { v3 = samples[(size_t)r3 * DIM + lane]; c3 = contexts[r3]; }
    c0 = __builtin_amdgcn_readfirstlane(c0);
    c1 = __builtin_amdgcn_readfirstlane(c1);
    c2 = __builtin_amdgcn_readfirstlane(c2);
    c3 = __builtin_amdgcn_readfirstlane(c3);
    ACCUM(c0, v0)
    ACCUM(c1, v1)
    ACCUM(c2, v2)
    ACCUM(c3, v3)
  }
#undef ACCUM

  // block-level reduce across the 4 waves (non-atomic), write partials
  __shared__ float red[4][NCTX * DIM];
  float* pb = part + (size_t)blockIdx.x * PART_STRIDE;

#pragma unroll
  for (int k = 0; k < NCTX; ++k) red[wv][k * DIM + lane] = s1a[k];
  __syncthreads();
  for (int i = tid; i < NCTX * DIM; i += 256)
    pb[i] = red[0][i] + red[1][i] + red[2][i] + red[3][i];
  __syncthreads();

#pragma unroll
  for (int k = 0; k < NCTX; ++k) red[wv][k * DIM + lane] = s2a[k];
  __syncthreads();
  for (int i = tid; i < NCTX * DIM; i += 256)
    pb[1024 + i] = red[0][i] + red[1][i] + red[2][i] + red[3][i];
  __syncthreads();

  if (lane == 0) {
#pragma unroll
    for (int k = 0; k < NCTX; ++k) red[wv][k] = cna[k];
  }
  __syncthreads();
  if (tid < NCTX)
    pb[2048 + tid] = red[0][tid] + red[1][tid] + red[2][tid] + red[3][tid];
}

// ------------- Pass 2a: tree-reduce partials (all CUs active) -------------
// 256 blocks = 16 contexts x 16 slices; each reduces nb/16 partial blocks.
__global__ __launch_bounds__(256) void reduce_a_kernel(
    const float* __restrict__ part, float* __restrict__ part2, int nb) {
  int c     = blockIdx.x & (NCTX - 1);
  int slice = blockIdx.x >> 4;
  int tid = threadIdx.x, d = tid & 63, g = tid >> 6;
  int per = nb / NSLICE;
  int b0  = slice * per;

  float a1 = 0.f, a2 = 0.f, ac = 0.f;
  for (int b = b0 + g; b < b0 + per; b += 4) {
    const float* p = part + (size_t)b * PART_STRIDE;
    a1 += p[c * DIM + d];
    a2 += p[1024 + c * DIM + d];
    if (d == 0) ac += p[2048 + c];
  }

  __shared__ float r1[4][DIM], r2[4][DIM], rc[4];
  r1[g][d] = a1;
  r2[g][d] = a2;
  if (d == 0) rc[g] = ac;
  __syncthreads();

  if (tid < DIM) {
    float* o = part2 + (size_t)(c * NSLICE + slice) * P2_STRIDE;
    o[tid]      = r1[0][tid] + r1[1][tid] + r1[2][tid] + r1[3][tid];
    o[64 + tid] = r2[0][tid] + r2[1][tid] + r2[2][tid] + r2[3][tid];
    if (tid == 0) o[128] = rc[0] + rc[1] + rc[2] + rc[3];
  }
}

// ------------- Pass 2b: final 16-way sum + scale/shift finalize -------------
__global__ __launch_bounds__(64) void finalize_kernel(
    const float* __restrict__ part2,
    const float* __restrict__ gamma,
    const float* __restrict__ beta,
    const float* __restrict__ priors,
    float* __restrict__ ws) {
  int c = blockIdx.x;
  int d = threadIdx.x;
  float s1 = 0.f, s2 = 0.f, cnt = 0.f;
#pragma unroll
  for (int s = 0; s < NSLICE; ++s) {
    const float* p = part2 + (size_t)(c * NSLICE + s) * P2_STRIDE;
    s1  += p[d];
    s2  += p[64 + d];
    cnt += p[128];
  }
  float safe = fmaxf(cnt, 1.f);
  float mean = s1 / safe;
  float var  = s2 / safe - mean * mean;
  float istd = rsqrtf(var + EPSV);
  float ps   = rsqrtf(priors[c]);
  float gm   = gamma[c * DIM + d];
  float scale = gm * istd * ps;
  float shift = (beta[c * DIM + d] - gm * mean * istd) * ps;
  if (!(cnt > 0.f)) { scale = 1.f; shift = 0.f; }  // where(cnt>0, y, x)
  ws[WS_SCALE + c * DIM + d] = scale;
  ws[WS_SHIFT + c * DIM + d] = shift;
}

// ---------------- Pass 3: y = x * scale[c] + shift[c] ----------------
__global__ __launch_bounds__(256) void norm_kernel(
    const float4* __restrict__ samples4,
    const int* __restrict__ contexts,
    const float* __restrict__ ws,
    float4* __restrict__ out4, int n4) {
  __shared__ float4 sc[NCTX * DIM / 4];
  __shared__ float4 sh[NCTX * DIM / 4];
  const float4* wsc = (const float4*)(ws + WS_SCALE);
  const float4* wsh = (const float4*)(ws + WS_SHIFT);
  for (int i = threadIdx.x; i < NCTX * DIM / 4; i += blockDim.x) {
    sc[i] = wsc[i];
    sh[i] = wsh[i];
  }
  __syncthreads();

  int stride = gridDim.x * blockDim.x;
  for (int i = blockIdx.x * blockDim.x + threadIdx.x; i < n4; i += stride) {
    int row = i >> 4;          // 16 float4 per row (D=64)
    int d4  = i & 15;
    int c   = contexts[row];
    float4 v = samples4[i];
    float4 a = sc[c * 16 + d4];
    float4 b = sh[c * 16 + d4];
    float4 r;
    r.x = fmaf(v.x, a.x, b.x);
    r.y = fmaf(v.y, a.y, b.y);
    r.z = fmaf(v.z, a.z, b.z);
    r.w = fmaf(v.w, a.w, b.w);
    out4[i] = r;
  }
}

extern "C" void kernel_launch(void* const* d_in, const int* in_sizes, int n_in,
                              void* d_out, int out_size, void* d_ws, size_t ws_size,
                              hipStream_t stream) {
  const float* samples  = (const float*)d_in[0];
  const int*   contexts = (const int*)d_in[1];
  const float* gamma    = (const float*)d_in[2];
  const float* beta     = (const float*)d_in[3];
  const float* priors   = (const float*)d_in[4];
  float* out = (float*)d_out;
  float* ws  = (float*)d_ws;

  int N = in_sizes[1];  // contexts has N elements

  // pick partial-block count that fits ws (~17 MB at nb=2048)
  size_t availf = ws_size / sizeof(float);
  int nb = 2048;
  while (nb > 256 &&
         (size_t)WS_PART + (size_t)nb * PART_STRIDE +
         (size_t)NCTX * NSLICE * P2_STRIDE > availf)
    nb >>= 1;

  float* part  = ws + WS_PART;
  float* part2 = part + (size_t)nb * PART_STRIDE;

  stats_kernel<<<nb, 256, 0, stream>>>(samples, contexts, part, N);
  reduce_a_kernel<<<NCTX * NSLICE, 256, 0, stream>>>(part, part2, nb);
  finalize_kernel<<<NCTX, 64, 0, stream>>>(part2, gamma, beta, priors, ws);

  int n4 = N * (DIM / 4);
  norm_kernel<<<4096, 256, 0, stream>>>((const float4*)samples, contexts, ws,
                                        (float4*)out, n4);
}

// Round 4
// 188.617 us; speedup vs baseline: 3.9050x; 1.1226x over previous
//
#include <hip/hip_runtime.h>

#define EPSV 0.001f
#define NCTX 16
#define DIM  64
#define NSLICE 16
#define PART_STRIDE 2080   // floats per partial block: s1[1024] s2[1024] cnt[16] pad
#define P2_STRIDE   132    // per (ctx,slice): s1[64] s2[64] cnt[1] pad

// ws layout (floats): [0,1024) scale; [1024,2048) shift;
// [2048, 2048+nb*PART_STRIDE) stage-1 partials; then 16*16*P2_STRIDE stage-2.
#define WS_SCALE 0
#define WS_SHIFT 1024
#define WS_PART  2048

// ---------------- Pass 1: branchless per-wave LDS accumulation ----------------
// Each wave owns acc[wv][ctx*64+lane] = (s1,s2) float2 (8 KB/wave, 32 KB/block).
// Per row: ds_read_b64 -> add/fma -> ds_write_b64 at c*64+lane. No branches
// (the old 16-way switch serialized on the CU's single scalar unit), no atomics.
// Counts: lane==c adds 1 in a register (lanes 0..15 hold the 16 ctx counts).
__global__ __launch_bounds__(256) void stats_kernel(
    const float* __restrict__ samples,
    const int* __restrict__ contexts,
    float* __restrict__ part, int N) {
  __shared__ float2 acc[4 * NCTX * DIM];   // 32 KB
  __shared__ float  cshare[4][NCTX];

  int tid  = threadIdx.x;
  int lane = tid & 63;
  int wv   = tid >> 6;

  for (int i = tid; i < 4 * NCTX * DIM; i += 256) acc[i] = make_float2(0.f, 0.f);
  __syncthreads();

  float2* my = acc + wv * (NCTX * DIM);
  float cntk = 0.f;

  int gw   = blockIdx.x * 4 + wv;
  int nw   = gridDim.x * 4;
  int step = nw * 4;

#define STLOAD(vv, cc, r)                                                  \
  do {                                                                     \
    if ((r) < N) {                                                         \
      vv = samples[(size_t)(r) * DIM + lane];                              \
      cc = contexts[r];                                                    \
    } else { vv = 0.f; cc = -1; }                                          \
  } while (0)

#define STPROC(vv, cc)                                                     \
  do {                                                                     \
    if ((cc) >= 0) {                                                       \
      float2 o = my[(cc) * DIM + lane];                                    \
      o.x += (vv);                                                         \
      o.y = fmaf((vv), (vv), o.y);                                         \
      my[(cc) * DIM + lane] = o;                                           \
      cntk += (lane == (cc)) ? 1.f : 0.f;                                  \
    }                                                                      \
  } while (0)

  if (gw < N) {
    float v0, v1, v2, v3;
    int   c0, c1, c2, c3;
    STLOAD(v0, c0, gw);
    STLOAD(v1, c1, gw + nw);
    STLOAD(v2, c2, gw + 2 * nw);
    STLOAD(v3, c3, gw + 3 * nw);
    for (int row = gw; row < N; ) {
      int nrow = row + step;
      float n0, n1, n2, n3;
      int   d0 = -1, d1 = -1, d2 = -1, d3 = -1;
      n0 = n1 = n2 = n3 = 0.f;
      if (nrow < N) {
        STLOAD(n0, d0, nrow);
        STLOAD(n1, d1, nrow + nw);
        STLOAD(n2, d2, nrow + 2 * nw);
        STLOAD(n3, d3, nrow + 3 * nw);
      }
      STPROC(v0, c0);
      STPROC(v1, c1);
      STPROC(v2, c2);
      STPROC(v3, c3);
      v0 = n0; c0 = d0; v1 = n1; c1 = d1;
      v2 = n2; c2 = d2; v3 = n3; c3 = d3;
      row = nrow;
    }
  }
#undef STLOAD
#undef STPROC

  __syncthreads();

  // cross-wave reduce, write per-block partials
  float* pb = part + (size_t)blockIdx.x * PART_STRIDE;
  for (int i = tid; i < NCTX * DIM; i += 256) {
    float2 a0 = acc[i];
    float2 a1 = acc[NCTX * DIM + i];
    float2 a2 = acc[2 * NCTX * DIM + i];
    float2 a3 = acc[3 * NCTX * DIM + i];
    pb[i]        = a0.x + a1.x + a2.x + a3.x;
    pb[1024 + i] = a0.y + a1.y + a2.y + a3.y;
  }
  if (lane < NCTX) cshare[wv][lane] = cntk;
  __syncthreads();
  if (tid < NCTX)
    pb[2048 + tid] = cshare[0][tid] + cshare[1][tid] +
                     cshare[2][tid] + cshare[3][tid];
}

// ------------- Pass 2a: tree-reduce partials (all CUs active) -------------
// 256 blocks = 16 contexts x 16 slices; each reduces nb/16 partial blocks.
__global__ __launch_bounds__(256) void reduce_a_kernel(
    const float* __restrict__ part, float* __restrict__ part2, int nb) {
  int c     = blockIdx.x & (NCTX - 1);
  int slice = blockIdx.x >> 4;
  int tid = threadIdx.x, d = tid & 63, g = tid >> 6;
  int per = nb / NSLICE;
  int b0  = slice * per;

  // 2 independent accumulator sets for latency hiding
  float a1 = 0.f, a2 = 0.f, ac = 0.f;
  float b1 = 0.f, b2 = 0.f, bc = 0.f;
  for (int b = b0 + g; b < b0 + per; b += 8) {
    const float* p = part + (size_t)b * PART_STRIDE;
    a1 += p[c * DIM + d];
    a2 += p[1024 + c * DIM + d];
    if (d == 0) ac += p[2048 + c];
    int bb = b + 4;
    if (bb < b0 + per) {
      const float* q = part + (size_t)bb * PART_STRIDE;
      b1 += q[c * DIM + d];
      b2 += q[1024 + c * DIM + d];
      if (d == 0) bc += q[2048 + c];
    }
  }
  a1 += b1; a2 += b2; ac += bc;

  __shared__ float r1[4][DIM], r2[4][DIM], rc[4];
  r1[g][d] = a1;
  r2[g][d] = a2;
  if (d == 0) rc[g] = ac;
  __syncthreads();

  if (tid < DIM) {
    float* o = part2 + (size_t)(c * NSLICE + slice) * P2_STRIDE;
    o[tid]      = r1[0][tid] + r1[1][tid] + r1[2][tid] + r1[3][tid];
    o[64 + tid] = r2[0][tid] + r2[1][tid] + r2[2][tid] + r2[3][tid];
    if (tid == 0) o[128] = rc[0] + rc[1] + rc[2] + rc[3];
  }
}

// ------------- Pass 2b: final 16-way sum + scale/shift finalize -------------
__global__ __launch_bounds__(64) void finalize_kernel(
    const float* __restrict__ part2,
    const float* __restrict__ gamma,
    const float* __restrict__ beta,
    const float* __restrict__ priors,
    float* __restrict__ ws) {
  int c = blockIdx.x;
  int d = threadIdx.x;
  float s1 = 0.f, s2 = 0.f, cnt = 0.f;
#pragma unroll
  for (int s = 0; s < NSLICE; ++s) {
    const float* p = part2 + (size_t)(c * NSLICE + s) * P2_STRIDE;
    s1  += p[d];
    s2  += p[64 + d];
    cnt += p[128];
  }
  float safe = fmaxf(cnt, 1.f);
  float mean = s1 / safe;
  float var  = s2 / safe - mean * mean;
  float istd = rsqrtf(var + EPSV);
  float ps   = rsqrtf(priors[c]);
  float gm   = gamma[c * DIM + d];
  float scale = gm * istd * ps;
  float shift = (beta[c * DIM + d] - gm * mean * istd) * ps;
  if (!(cnt > 0.f)) { scale = 1.f; shift = 0.f; }  // where(cnt>0, y, x)
  ws[WS_SCALE + c * DIM + d] = scale;
  ws[WS_SHIFT + c * DIM + d] = shift;
}

// ---------------- Pass 3: y = x * scale[c] + shift[c] ----------------
__global__ __launch_bounds__(256) void norm_kernel(
    const float4* __restrict__ samples4,
    const int* __restrict__ contexts,
    const float* __restrict__ ws,
    float4* __restrict__ out4, int n4) {
  __shared__ float4 sc[NCTX * DIM / 4];
  __shared__ float4 sh[NCTX * DIM / 4];
  const float4* wsc = (const float4*)(ws + WS_SCALE);
  const float4* wsh = (const float4*)(ws + WS_SHIFT);
  for (int i = threadIdx.x; i < NCTX * DIM / 4; i += blockDim.x) {
    sc[i] = wsc[i];
    sh[i] = wsh[i];
  }
  __syncthreads();

  int stride = gridDim.x * blockDim.x;
  for (int i = blockIdx.x * blockDim.x + threadIdx.x; i < n4; i += stride) {
    int row = i >> 4;          // 16 float4 per row (D=64)
    int d4  = i & 15;
    int c   = contexts[row];
    float4 v = samples4[i];
    float4 a = sc[c * 16 + d4];
    float4 b = sh[c * 16 + d4];
    float4 r;
    r.x = fmaf(v.x, a.x, b.x);
    r.y = fmaf(v.y, a.y, b.y);
    r.z = fmaf(v.z, a.z, b.z);
    r.w = fmaf(v.w, a.w, b.w);
    out4[i] = r;
  }
}

extern "C" void kernel_launch(void* const* d_in, const int* in_sizes, int n_in,
                              void* d_out, int out_size, void* d_ws, size_t ws_size,
                              hipStream_t stream) {
  const float* samples  = (const float*)d_in[0];
  const int*   contexts = (const int*)d_in[1];
  const float* gamma    = (const float*)d_in[2];
  const float* beta     = (const float*)d_in[3];
  const float* priors   = (const float*)d_in[4];
  float* out = (float*)d_out;
  float* ws  = (float*)d_ws;

  int N = in_sizes[1];  // contexts has N elements

  // pick partial-block count that fits ws (~17 MB at nb=2048)
  size_t availf = ws_size / sizeof(float);
  int nb = 2048;
  while (nb > 256 &&
         (size_t)WS_PART + (size_t)nb * PART_STRIDE +
         (size_t)NCTX * NSLICE * P2_STRIDE > availf)
    nb >>= 1;

  float* part  = ws + WS_PART;
  float* part2 = part + (size_t)nb * PART_STRIDE;

  stats_kernel<<<nb, 256, 0, stream>>>(samples, contexts, part, N);
  reduce_a_kernel<<<NCTX * NSLICE, 256, 0, stream>>>(part, part2, nb);
  finalize_kernel<<<NCTX, 64, 0, stream>>>(part2, gamma, beta, priors, ws);

  int n4 = N * (DIM / 4);
  norm_kernel<<<4096, 256, 0, stream>>>((const float4*)samples, contexts, ws,
                                        (float4*)out, n4);
}